// Round 1
// baseline (176.788 us; speedup 1.0000x reference)
//
#include <hip/hip_runtime.h>

// Problem dims (ViT-Base LoRA-MoE qkv)
#define TOK 8192      // B*S = 32*256
#define DD  768       // in features
#define NOUT 2304     // 3*D
#define TT  8         // saved tasks
#define RR  16        // LoRA rank
#define KRANK 144     // T*R + R (per branch folded rank)

typedef __bf16 bf16;
typedef __bf16 bf16x4 __attribute__((ext_vector_type(4)));
typedef __bf16 bf16x8 __attribute__((ext_vector_type(8)));
typedef float  floatx4 __attribute__((ext_vector_type(4)));

__device__ __forceinline__ void gl_lds16(const void* g, void* l) {
    __builtin_amdgcn_global_load_lds((const __attribute__((address_space(1))) void*)g,
                                     (__attribute__((address_space(3))) void*)l, 16, 0, 0);
}

// ----------------------------------------------------------------- prep ----
// blocks 0..31: Frobenius norms of {A_q,B_q,A_v,B_v}[task]  (b>>3 selects
// tensor, b&7 selects task). blocks 32..3103: fp32->bf16 cast of x,
// 8 elems/thread (R7: was 4; bf16x8 16B stores).
__global__ __launch_bounds__(256) void prep_kernel(
    const float* __restrict__ A_q, const float* __restrict__ B_q,
    const float* __restrict__ A_v, const float* __restrict__ B_v,
    const float* __restrict__ x, bf16* __restrict__ xb,
    float* __restrict__ norms)
{
    __shared__ float ws4[4];
    const int b = blockIdx.x;
    if (b < 32) {
        const float* base;
        switch (b >> 3) {
            case 0: base = A_q; break;
            case 1: base = B_q; break;
            case 2: base = A_v; break;
            default: base = B_v; break;
        }
        base += (b & 7) * (RR * DD);
        float s = 0.f;
        for (int i = threadIdx.x; i < RR * DD; i += 256) {
            float v = base[i];
            s = fmaf(v, v, s);
        }
        #pragma unroll
        for (int off = 32; off > 0; off >>= 1) s += __shfl_down(s, off);
        if ((threadIdx.x & 63) == 0) ws4[threadIdx.x >> 6] = s;
        __syncthreads();
        if (threadIdx.x == 0)
            norms[b] = sqrtf(ws4[0] + ws4[1] + ws4[2] + ws4[3]);
    } else {
        const int idx = ((b - 32) * 256 + threadIdx.x) * 8;
        const float4 v0 = *(const float4*)(x + idx);
        const float4 v1 = *(const float4*)(x + idx + 4);
        bf16x8 o = { (bf16)v0.x, (bf16)v0.y, (bf16)v0.z, (bf16)v0.w,
                     (bf16)v1.x, (bf16)v1.y, (bf16)v1.z, (bf16)v1.w };
        *(bf16x8*)(xb + idx) = o;
    }
}

// ----------------------------------------------------------------- fold ----
// Wc[row] = bf16(qkv_w[row] + sum_i c[row][i] * Acat[i][:]) for q/v thirds;
// plain bf16 cast for the k third. Softmax gate + norm scaling computed
// inline per block. grid = (3, 288).  (unchanged, verified)
__global__ __launch_bounds__(256) void fold_kernel(
    const float* __restrict__ qkv_w,
    const float* __restrict__ A_q, const float* __restrict__ la_q,
    const float* __restrict__ B_q, const float* __restrict__ lb_q,
    const float* __restrict__ A_v, const float* __restrict__ la_v,
    const float* __restrict__ B_v, const float* __restrict__ lb_v,
    const float* __restrict__ gate_logits, const float* __restrict__ alpha,
    const float* __restrict__ norms, bf16* __restrict__ Wc)
{
    const int tid = threadIdx.x;
    const int d = blockIdx.x * 256 + tid;
    const int gy = blockIdx.y;

    if (gy >= 96 && gy < 192) {           // k third: pure cast
        const int rowbase = DD + (gy - 96) * 8;
        #pragma unroll
        for (int j = 0; j < 8; ++j) {
            const int row = rowbase + j;
            Wc[row * DD + d] = (bf16)qkv_w[row * DD + d];
        }
        return;
    }

    __shared__ float c_lds[8 * KRANK];
    __shared__ float sc_sh[TT];
    __shared__ float acur_sh;

    const bool is_v = (gy >= 192);
    const int e0 = (is_v ? gy - 192 : gy) * 8;
    const float* Astack = is_v ? A_v : A_q;
    const float* la     = is_v ? la_v : la_q;
    const float* Bmat   = is_v ? B_v : B_q;
    const float* lb     = is_v ? lb_v : lb_q;
    const float* nA     = norms + (is_v ? 16 : 0);
    const float* nB     = norms + (is_v ? 24 : 8);
    const int rowbase   = (is_v ? 2 * DD : 0) + e0;

    if (tid == 0) {
        float mx = gate_logits[0];
        for (int t = 1; t < TT; ++t) mx = fmaxf(mx, gate_logits[t]);
        float e[TT], s = 0.f;
        for (int t = 0; t < TT; ++t) { e[t] = __expf(gate_logits[t] - mx); s += e[t]; }
        for (int t = 0; t < TT; ++t) sc_sh[t] = (e[t] / s) / (nA[t] * nB[t]);
        acur_sh = alpha[TT];
    }
    __syncthreads();

    for (int idx = tid; idx < 8 * KRANK; idx += 256) {
        const int j = idx / KRANK, i = idx - j * KRANK;
        const int e = e0 + j;
        float v;
        if (i < TT * RR) {
            const int t = i >> 4, r = i & 15;
            v = sc_sh[t] * Bmat[(t * DD + e) * RR + r];
        } else {
            v = acur_sh * lb[e * RR + (i - TT * RR)];
        }
        c_lds[j * KRANK + i] = v;
    }
    __syncthreads();

    float acc[8] = {0.f, 0.f, 0.f, 0.f, 0.f, 0.f, 0.f, 0.f};

    for (int i = 0; i < TT * RR; i += 4) {
        const float a0 = Astack[(i + 0) * DD + d];
        const float a1 = Astack[(i + 1) * DD + d];
        const float a2 = Astack[(i + 2) * DD + d];
        const float a3 = Astack[(i + 3) * DD + d];
        #pragma unroll
        for (int j = 0; j < 8; ++j) {
            const float4 cv = *(const float4*)&c_lds[j * KRANK + i];
            acc[j] = fmaf(a0, cv.x, fmaf(a1, cv.y, fmaf(a2, cv.z, fmaf(a3, cv.w, acc[j]))));
        }
    }
    #pragma unroll
    for (int i = 0; i < RR; i += 4) {
        const float a0 = la[(i + 0) * DD + d];
        const float a1 = la[(i + 1) * DD + d];
        const float a2 = la[(i + 2) * DD + d];
        const float a3 = la[(i + 3) * DD + d];
        #pragma unroll
        for (int j = 0; j < 8; ++j) {
            const float4 cv = *(const float4*)&c_lds[j * KRANK + TT * RR + i];
            acc[j] = fmaf(a0, cv.x, fmaf(a1, cv.y, fmaf(a2, cv.z, fmaf(a3, cv.w, acc[j]))));
        }
    }

    #pragma unroll
    for (int j = 0; j < 8; ++j) {
        const int row = rowbase + j;
        Wc[row * DD + d] = (bf16)(qkv_w[row * DD + d] + acc[j]);
    }
}

// ----------------------------------------------------------------- gemm ----
// C[TOK,NOUT] = Xbf[TOK,DD] @ Wc[NOUT,DD]^T + bias.
// R7: T3/T4 counted-vmcnt double-buffered pipeline (catalog "minimum
// 2-phase"). Tile 128x144, BK=64, LDS dbuf = 2*(16KB A + 18KB B) = 68KB ->
// still 2 blocks/CU (136KB <= 160KB). Grid = 64m x 16n = 1024 blocks =
// exactly 2 residency rounds (1024%8==0, XCD swizzle bijective).
// Loop: issue next K-tile gl_lds -> s_waitcnt vmcnt(8) (counted, never 0
// in-loop; per-wave chunk counts are 9/9/8/8 so 8 is uniformly safe) ->
// raw s_barrier -> ds_read + 36 MFMA -> s_barrier. Prefetch loads stay in
// flight across the compute phase instead of the old full vmcnt(0) drain
// (the m97-structure ~20% stall). Race check: RAW on buf[cur] guarded by
// own-wave counted vmcnt + barrier (all waves drain own loads before
// barrier); WAR on buf[cur^1] guarded by the post-compute barrier (all
// ds_reads consumed by MFMA before it).
// Kept (verified): gl_lds dwordx4 staging, XOR 16B-chunk swizzle (0
// conflicts), XCD block swizzle, m89 C/D layout, direct-store epilogue.
// Per wave: 32x144 output = 2x9 16x16 tiles, acc = 72 VGPR (halved vs R6
// -> more scheduler headroom, no spill risk).
__global__ __launch_bounds__(256, 2) void gemm_kernel(
    const bf16* __restrict__ A, const bf16* __restrict__ B,
    const float* __restrict__ bias, float* __restrict__ C)
{
    __shared__ __align__(16) char smem[69632];   // 2x(128x64) A + 2x(144x64) B bf16
    bf16* const lds_a = (bf16*)smem;             // buf stride 8192 bf16 (16KB)
    bf16* const lds_b = (bf16*)(smem + 32768);   // buf stride 9216 bf16 (18KB)

    const int tid  = threadIdx.x;
    const int lane = tid & 63;
    const int wave = tid >> 6;

    // XCD swizzle: 1024 blocks = 8 XCD x (8 m-tiles x 16 n-tiles)
    const int flat  = blockIdx.x;
    const int xcd   = flat & 7;
    const int local = flat >> 3;            // 0..127
    const int mb    = xcd * 8 + (local & 7);   // 0..63
    const int nb    = local >> 3;              // 0..15
    const int m0 = mb * 128;
    const int n0 = nb * 144;

    // 4 waves split M: each wave computes 32x144 (2x9 tiles of 16x16)
    const int wm = wave * 32;

    // staging: lane l -> slot l (16B) within a 1KB chunk (8 rows x 64 bf16).
    // logical row = l>>3, logical 16B chunk = (l&7) ^ (l>>3)  (XOR swizzle).
    const int srow = lane >> 3;                    // 0..7
    const int scol = ((lane & 7) ^ srow) * 8;      // swizzled col (bf16 units)

    floatx4 acc[2][9];
    #pragma unroll
    for (int i = 0; i < 2; ++i)
        #pragma unroll
        for (int j = 0; j < 9; ++j)
            acc[i][j] = (floatx4){0.f, 0.f, 0.f, 0.f};

    const bf16* const gA = A + (m0 + srow) * DD + scol;
    const bf16* const gB = B + (n0 + srow) * DD + scol;

    // 34 chunks/K-step: 0..15 A (128 rows), 16..33 B (144 rows).
    // wave round-robin -> counts 9/9/8/8.
    auto stage = [&](int buf, int k0) {
        bf16* la = lds_a + buf * (128 * 64);
        bf16* lb = lds_b + buf * (144 * 64);
        for (int c = wave; c < 34; c += 4) {
            if (c < 16) gl_lds16(gA + c * 8 * DD + k0, la + c * 512);
            else        gl_lds16(gB + (c - 16) * 8 * DD + k0, lb + (c - 16) * 512);
        }
    };

    stage(0, 0);    // prologue prefetch

    for (int kt = 0; kt < 12; ++kt) {
        const int cur = kt & 1;
        if (kt < 11) {
            stage(cur ^ 1, (kt + 1) * 64);
            // counted wait: drains prior K-tile's loads, leaves (most of)
            // this issue batch in flight across the compute phase.
            asm volatile("s_waitcnt vmcnt(8)" ::: "memory");
        } else {
            asm volatile("s_waitcnt vmcnt(0)" ::: "memory");
        }
        __builtin_amdgcn_s_barrier();
        asm volatile("" ::: "memory");   // fence: no LDS read hoists above barrier

        const bf16* la = lds_a + cur * (128 * 64);
        const bf16* lb = lds_b + cur * (144 * 64);
        #pragma unroll
        for (int ks = 0; ks < 2; ++ks) {
            const int c_log = ks * 4 + (lane >> 4); // 16B chunk index 0..7
            bf16x8 af[2];
            #pragma unroll
            for (int mt = 0; mt < 2; ++mt) {
                const int r = wm + mt * 16 + (lane & 15);
                af[mt] = *(const bf16x8*)&la[r * 64 + ((c_log ^ (r & 7)) * 8)];
            }
            #pragma unroll
            for (int nt = 0; nt < 9; ++nt) {
                const int r = nt * 16 + (lane & 15);
                const bf16x8 bfr = *(const bf16x8*)&lb[r * 64 + ((c_log ^ (r & 7)) * 8)];
                #pragma unroll
                for (int mt = 0; mt < 2; ++mt)
                    acc[mt][nt] = __builtin_amdgcn_mfma_f32_16x16x32_bf16(
                        af[mt], bfr, acc[mt][nt], 0, 0, 0);
            }
        }
        asm volatile("" ::: "memory");   // fence: reads complete before release
        __builtin_amdgcn_s_barrier();    // all waves done reading buf[cur]
    }

    // epilogue: direct stores. C/D layout col=lane&15, row=(lane>>4)*4+reg
    const int cr = (lane >> 4) * 4;
    const int cc = lane & 15;
    #pragma unroll
    for (int nt = 0; nt < 9; ++nt) {
        const int gn = n0 + nt * 16 + cc;
        const float bv = bias[gn];
        #pragma unroll
        for (int mt = 0; mt < 2; ++mt) {
            const int gm = m0 + wm + mt * 16 + cr;
            #pragma unroll
            for (int r = 0; r < 4; ++r)
                C[(gm + r) * NOUT + gn] = acc[mt][nt][r] + bv;
        }
    }
}

// --------------------------------------------------------------- launch ----
extern "C" void kernel_launch(void* const* d_in, const int* in_sizes, int n_in,
                              void* d_out, int out_size, void* d_ws, size_t ws_size,
                              hipStream_t stream)
{
    const float* x           = (const float*)d_in[0];
    const float* qkv_w       = (const float*)d_in[1];
    const float* qkv_b       = (const float*)d_in[2];
    const float* la_q        = (const float*)d_in[3];
    const float* lb_q        = (const float*)d_in[4];
    const float* la_v        = (const float*)d_in[5];
    const float* lb_v        = (const float*)d_in[6];
    const float* A_q         = (const float*)d_in[7];
    const float* B_q         = (const float*)d_in[8];
    const float* A_v         = (const float*)d_in[9];
    const float* B_v         = (const float*)d_in[10];
    const float* gate_logits = (const float*)d_in[11];
    const float* alpha       = (const float*)d_in[12];
    float* out = (float*)d_out;

    char* ws = (char*)d_ws;
    bf16*  Xbf    = (bf16*)ws;                                  // 12,582,912 B
    bf16*  Wc     = (bf16*)(ws + 12582912);                     //  3,538,944 B
    float* norms  = (float*)(ws + 12582912 + 3538944);          // 32 floats

    prep_kernel<<<32 + TOK * DD / 2048, 256, 0, stream>>>(A_q, B_q, A_v, B_v,
                                                          x, Xbf, norms);
    fold_kernel<<<dim3(3, 288), 256, 0, stream>>>(qkv_w,
                                                  A_q, la_q, B_q, lb_q,
                                                  A_v, la_v, B_v, lb_v,
                                                  gate_logits, alpha, norms, Wc);
    gemm_kernel<<<1024, 256, 0, stream>>>(Xbf, Wc, qkv_b, out);
}

// Round 2
// 176.773 us; speedup vs baseline: 1.0001x; 1.0001x over previous
//
#include <hip/hip_runtime.h>

// Problem dims (ViT-Base LoRA-MoE qkv)
#define TOK 8192      // B*S = 32*256
#define DD  768       // in features
#define NOUT 2304     // 3*D
#define TT  8         // saved tasks
#define RR  16        // LoRA rank
#define KRANK 144     // T*R + R (per branch folded rank)

typedef __bf16 bf16;
typedef __bf16 bf16x4 __attribute__((ext_vector_type(4)));
typedef __bf16 bf16x8 __attribute__((ext_vector_type(8)));
typedef float  floatx4 __attribute__((ext_vector_type(4)));

__device__ __forceinline__ void gl_lds16(const void* g, void* l) {
    __builtin_amdgcn_global_load_lds((const __attribute__((address_space(1))) void*)g,
                                     (__attribute__((address_space(3))) void*)l, 16, 0, 0);
}

// ----------------------------------------------------------------- prep ----
// blocks 0..31: Frobenius norms of {A_q,B_q,A_v,B_v}[task]  (b>>3 selects
// tensor, b&7 selects task). blocks 32..3103: fp32->bf16 cast of x,
// 8 elems/thread (bf16x8 16B stores).
__global__ __launch_bounds__(256) void prep_kernel(
    const float* __restrict__ A_q, const float* __restrict__ B_q,
    const float* __restrict__ A_v, const float* __restrict__ B_v,
    const float* __restrict__ x, bf16* __restrict__ xb,
    float* __restrict__ norms)
{
    __shared__ float ws4[4];
    const int b = blockIdx.x;
    if (b < 32) {
        const float* base;
        switch (b >> 3) {
            case 0: base = A_q; break;
            case 1: base = B_q; break;
            case 2: base = A_v; break;
            default: base = B_v; break;
        }
        base += (b & 7) * (RR * DD);
        float s = 0.f;
        for (int i = threadIdx.x; i < RR * DD; i += 256) {
            float v = base[i];
            s = fmaf(v, v, s);
        }
        #pragma unroll
        for (int off = 32; off > 0; off >>= 1) s += __shfl_down(s, off);
        if ((threadIdx.x & 63) == 0) ws4[threadIdx.x >> 6] = s;
        __syncthreads();
        if (threadIdx.x == 0)
            norms[b] = sqrtf(ws4[0] + ws4[1] + ws4[2] + ws4[3]);
    } else {
        const int idx = ((b - 32) * 256 + threadIdx.x) * 8;
        const float4 v0 = *(const float4*)(x + idx);
        const float4 v1 = *(const float4*)(x + idx + 4);
        bf16x8 o = { (bf16)v0.x, (bf16)v0.y, (bf16)v0.z, (bf16)v0.w,
                     (bf16)v1.x, (bf16)v1.y, (bf16)v1.z, (bf16)v1.w };
        *(bf16x8*)(xb + idx) = o;
    }
}

// ----------------------------------------------------------------- fold ----
// Wc[row] = bf16(qkv_w[row] + sum_i c[row][i] * Acat[i][:]) for q/v thirds;
// plain bf16 cast for the k third. Softmax gate + norm scaling computed
// inline per block. grid = (3, 288).  (unchanged, verified)
__global__ __launch_bounds__(256) void fold_kernel(
    const float* __restrict__ qkv_w,
    const float* __restrict__ A_q, const float* __restrict__ la_q,
    const float* __restrict__ B_q, const float* __restrict__ lb_q,
    const float* __restrict__ A_v, const float* __restrict__ la_v,
    const float* __restrict__ B_v, const float* __restrict__ lb_v,
    const float* __restrict__ gate_logits, const float* __restrict__ alpha,
    const float* __restrict__ norms, bf16* __restrict__ Wc)
{
    const int tid = threadIdx.x;
    const int d = blockIdx.x * 256 + tid;
    const int gy = blockIdx.y;

    if (gy >= 96 && gy < 192) {           // k third: pure cast
        const int rowbase = DD + (gy - 96) * 8;
        #pragma unroll
        for (int j = 0; j < 8; ++j) {
            const int row = rowbase + j;
            Wc[row * DD + d] = (bf16)qkv_w[row * DD + d];
        }
        return;
    }

    __shared__ float c_lds[8 * KRANK];
    __shared__ float sc_sh[TT];
    __shared__ float acur_sh;

    const bool is_v = (gy >= 192);
    const int e0 = (is_v ? gy - 192 : gy) * 8;
    const float* Astack = is_v ? A_v : A_q;
    const float* la     = is_v ? la_v : la_q;
    const float* Bmat   = is_v ? B_v : B_q;
    const float* lb     = is_v ? lb_v : lb_q;
    const float* nA     = norms + (is_v ? 16 : 0);
    const float* nB     = norms + (is_v ? 24 : 8);
    const int rowbase   = (is_v ? 2 * DD : 0) + e0;

    if (tid == 0) {
        float mx = gate_logits[0];
        for (int t = 1; t < TT; ++t) mx = fmaxf(mx, gate_logits[t]);
        float e[TT], s = 0.f;
        for (int t = 0; t < TT; ++t) { e[t] = __expf(gate_logits[t] - mx); s += e[t]; }
        for (int t = 0; t < TT; ++t) sc_sh[t] = (e[t] / s) / (nA[t] * nB[t]);
        acur_sh = alpha[TT];
    }
    __syncthreads();

    for (int idx = tid; idx < 8 * KRANK; idx += 256) {
        const int j = idx / KRANK, i = idx - j * KRANK;
        const int e = e0 + j;
        float v;
        if (i < TT * RR) {
            const int t = i >> 4, r = i & 15;
            v = sc_sh[t] * Bmat[(t * DD + e) * RR + r];
        } else {
            v = acur_sh * lb[e * RR + (i - TT * RR)];
        }
        c_lds[j * KRANK + i] = v;
    }
    __syncthreads();

    float acc[8] = {0.f, 0.f, 0.f, 0.f, 0.f, 0.f, 0.f, 0.f};

    for (int i = 0; i < TT * RR; i += 4) {
        const float a0 = Astack[(i + 0) * DD + d];
        const float a1 = Astack[(i + 1) * DD + d];
        const float a2 = Astack[(i + 2) * DD + d];
        const float a3 = Astack[(i + 3) * DD + d];
        #pragma unroll
        for (int j = 0; j < 8; ++j) {
            const float4 cv = *(const float4*)&c_lds[j * KRANK + i];
            acc[j] = fmaf(a0, cv.x, fmaf(a1, cv.y, fmaf(a2, cv.z, fmaf(a3, cv.w, acc[j]))));
        }
    }
    #pragma unroll
    for (int i = 0; i < RR; i += 4) {
        const float a0 = la[(i + 0) * DD + d];
        const float a1 = la[(i + 1) * DD + d];
        const float a2 = la[(i + 2) * DD + d];
        const float a3 = la[(i + 3) * DD + d];
        #pragma unroll
        for (int j = 0; j < 8; ++j) {
            const float4 cv = *(const float4*)&c_lds[j * KRANK + TT * RR + i];
            acc[j] = fmaf(a0, cv.x, fmaf(a1, cv.y, fmaf(a2, cv.z, fmaf(a3, cv.w, acc[j]))));
        }
    }

    #pragma unroll
    for (int j = 0; j < 8; ++j) {
        const int row = rowbase + j;
        Wc[row * DD + d] = (bf16)(qkv_w[row * DD + d] + acc[j]);
    }
}

// ----------------------------------------------------------------- gemm ----
// C[TOK,NOUT] = Xbf[TOK,DD] @ Wc[NOUT,DD]^T + bias.
// R8: R6 geometry EXACTLY preserved (128x288 tile, 512 blocks = 1 residency
// round at 2 blocks/CU, 52KB LDS, 4 waves 2x2 -> 64x144/wave, 4x9 acc) —
// single-variable change: BK 64->32 with LDS double-buffer + counted vmcnt.
// Removes R6's 12 full vmcnt(0) drains (the documented ~20% m97-class
// barrier-drain stall) while keeping every R4/R5/R6-pinned residency factor
// fixed. R7's regression was attributed to 2x residency rounds, not the
// pipeline — this isolates the pipeline.
// Loop (24 steps of BK=32): issue next K-tile gl_lds (26 chunks, 7/7/6/6
// per wave) -> s_waitcnt vmcnt(6) (drains exactly the current tile's loads,
// oldest-first; never 0 in-loop) -> raw s_barrier -> 13 ds_read_b128 +
// 36 MFMA per wave -> s_barrier. RAW on buf[cur]: own counted drain +
// barrier. WAR on buf[cur^1]: post-compute barrier. (R7-proven discipline.)
// BK=32 chunk = 16 rows x 32 bf16 (1KB); lane l -> row l>>2, 16B slot
// (l&3)^(row&3) (XOR swizzle). Read: 64 lanes = full permutation of a 1KB
// chunk region (8 dword-accesses/bank = floor) -> conflict-free.
__global__ __launch_bounds__(256, 2) void gemm_kernel(
    const bf16* __restrict__ A, const bf16* __restrict__ B,
    const float* __restrict__ bias, float* __restrict__ C)
{
    __shared__ __align__(16) char smem[53248];   // 2x(128x32) A + 2x(288x32) B bf16
    bf16* const lds_a = (bf16*)smem;             // buf stride 4096 bf16 (8KB)
    bf16* const lds_b = (bf16*)(smem + 16384);   // buf stride 9216 bf16 (18KB)

    const int tid  = threadIdx.x;
    const int lane = tid & 63;
    const int wave = tid >> 6;

    // XCD swizzle: 512 blocks = 8 XCD x (8 m-tiles x 8 n-tiles)
    const int flat  = blockIdx.x;
    const int xcd   = flat & 7;
    const int local = flat >> 3;           // 0..63
    const int mb    = xcd * 8 + (local & 7);
    const int nb    = local >> 3;          // 0..7
    const int m0 = mb * 128;
    const int n0 = nb * 288;

    // 4 waves: 2x2, each computes 64x144 (4x9 tiles of 16x16)
    const int wm = (wave >> 1) * 64;
    const int wn = (wave & 1) * 144;

    // staging (BK=32): chunk = 1KB = 16 rows x 32 bf16.
    // lane l -> row l>>2 (0..15), swizzled 16B slot ((l&3) ^ (row&3)).
    const int srow = lane >> 2;                        // 0..15
    const int scol = ((lane & 3) ^ (srow & 3)) * 8;    // swizzled col (bf16)

    floatx4 acc[4][9];
    #pragma unroll
    for (int i = 0; i < 4; ++i)
        #pragma unroll
        for (int j = 0; j < 9; ++j)
            acc[i][j] = (floatx4){0.f, 0.f, 0.f, 0.f};

    const bf16* const gA = A + (m0 + srow) * DD + scol;
    const bf16* const gB = B + (n0 + srow) * DD + scol;

    // 26 chunks/K-step: 0..7 A (128 rows), 8..25 B (288 rows).
    // wave round-robin -> counts 7/7/6/6.
    auto stage = [&](int buf, int k0) {
        bf16* la = lds_a + buf * (128 * 32);
        bf16* lb = lds_b + buf * (288 * 32);
        for (int c = wave; c < 26; c += 4) {
            if (c < 8) gl_lds16(gA + c * 16 * DD + k0, la + c * 512);
            else       gl_lds16(gB + (c - 8) * 16 * DD + k0, lb + (c - 8) * 512);
        }
    };

    stage(0, 0);    // prologue prefetch

    for (int kt = 0; kt < 24; ++kt) {
        const int cur = kt & 1;
        if (kt < 23) {
            stage(cur ^ 1, (kt + 1) * 32);
            // counted wait: drains current K-tile's loads (oldest first),
            // leaves the just-issued prefetch batch in flight across compute.
            asm volatile("s_waitcnt vmcnt(6)" ::: "memory");
        } else {
            asm volatile("s_waitcnt vmcnt(0)" ::: "memory");
        }
        __builtin_amdgcn_s_barrier();
        asm volatile("" ::: "memory");   // fence: no LDS read hoists above barrier

        const bf16* la = lds_a + cur * (128 * 32);
        const bf16* lb = lds_b + cur * (288 * 32);
        const int c_log = lane >> 4;              // 16B chunk index 0..3 (K=32)
        const int swz = (c_log ^ (lane & 3)) * 8; // row&3 == lane&3 for all frags
        bf16x8 af[4];
        #pragma unroll
        for (int mt = 0; mt < 4; ++mt) {
            const int r = wm + mt * 16 + (lane & 15);
            af[mt] = *(const bf16x8*)&la[r * 32 + swz];
        }
        #pragma unroll
        for (int nt = 0; nt < 9; ++nt) {
            const int r = wn + nt * 16 + (lane & 15);
            const bf16x8 bfr = *(const bf16x8*)&lb[r * 32 + swz];
            #pragma unroll
            for (int mt = 0; mt < 4; ++mt)
                acc[mt][nt] = __builtin_amdgcn_mfma_f32_16x16x32_bf16(
                    af[mt], bfr, acc[mt][nt], 0, 0, 0);
        }
        asm volatile("" ::: "memory");   // fence: reads complete before release
        __builtin_amdgcn_s_barrier();    // all waves done reading buf[cur]
    }

    // epilogue: direct stores. C/D layout col=lane&15, row=(lane>>4)*4+reg
    const int cr = (lane >> 4) * 4;
    const int cc = lane & 15;
    #pragma unroll
    for (int nt = 0; nt < 9; ++nt) {
        const int gn = n0 + wn + nt * 16 + cc;
        const float bv = bias[gn];
        #pragma unroll
        for (int mt = 0; mt < 4; ++mt) {
            const int gmb = m0 + wm + mt * 16 + cr;
            #pragma unroll
            for (int r = 0; r < 4; ++r)
                C[(gmb + r) * NOUT + gn] = acc[mt][nt][r] + bv;
        }
    }
}

// --------------------------------------------------------------- launch ----
extern "C" void kernel_launch(void* const* d_in, const int* in_sizes, int n_in,
                              void* d_out, int out_size, void* d_ws, size_t ws_size,
                              hipStream_t stream)
{
    const float* x           = (const float*)d_in[0];
    const float* qkv_w       = (const float*)d_in[1];
    const float* qkv_b       = (const float*)d_in[2];
    const float* la_q        = (const float*)d_in[3];
    const float* lb_q        = (const float*)d_in[4];
    const float* la_v        = (const float*)d_in[5];
    const float* lb_v        = (const float*)d_in[6];
    const float* A_q         = (const float*)d_in[7];
    const float* B_q         = (const float*)d_in[8];
    const float* A_v         = (const float*)d_in[9];
    const float* B_v         = (const float*)d_in[10];
    const float* gate_logits = (const float*)d_in[11];
    const float* alpha       = (const float*)d_in[12];
    float* out = (float*)d_out;

    char* ws = (char*)d_ws;
    bf16*  Xbf    = (bf16*)ws;                                  // 12,582,912 B
    bf16*  Wc     = (bf16*)(ws + 12582912);                     //  3,538,944 B
    float* norms  = (float*)(ws + 12582912 + 3538944);          // 32 floats

    prep_kernel<<<32 + TOK * DD / 2048, 256, 0, stream>>>(A_q, B_q, A_v, B_v,
                                                          x, Xbf, norms);
    fold_kernel<<<dim3(3, 288), 256, 0, stream>>>(qkv_w,
                                                  A_q, la_q, B_q, lb_q,
                                                  A_v, la_v, B_v, lb_v,
                                                  gate_logits, alpha, norms, Wc);
    gemm_kernel<<<512, 256, 0, stream>>>(Xbf, Wc, qkv_b, out);
}

// Round 3
// 171.253 us; speedup vs baseline: 1.0323x; 1.0322x over previous
//
#include <hip/hip_runtime.h>

// Problem dims (ViT-Base LoRA-MoE qkv)
#define TOK 8192      // B*S = 32*256
#define DD  768       // in features
#define NOUT 2304     // 3*D
#define TT  8         // saved tasks
#define RR  16        // LoRA rank
#define KRANK 144     // T*R + R (per branch folded rank)

typedef __bf16 bf16;
typedef __bf16 bf16x4 __attribute__((ext_vector_type(4)));
typedef __bf16 bf16x8 __attribute__((ext_vector_type(8)));
typedef float  floatx4 __attribute__((ext_vector_type(4)));

__device__ __forceinline__ void gl_lds16(const void* g, void* l) {
    __builtin_amdgcn_global_load_lds((const __attribute__((address_space(1))) void*)g,
                                     (__attribute__((address_space(3))) void*)l, 16, 0, 0);
}

// ----------------------------------------------------------------- prep ----
// blocks 0..31: Frobenius norms of {A_q,B_q,A_v,B_v}[task]  (b>>3 selects
// tensor, b&7 selects task). blocks 32..3103: fp32->bf16 cast of x,
// 8 elems/thread (bf16x8 16B stores).
__global__ __launch_bounds__(256) void prep_kernel(
    const float* __restrict__ A_q, const float* __restrict__ B_q,
    const float* __restrict__ A_v, const float* __restrict__ B_v,
    const float* __restrict__ x, bf16* __restrict__ xb,
    float* __restrict__ norms)
{
    __shared__ float ws4[4];
    const int b = blockIdx.x;
    if (b < 32) {
        const float* base;
        switch (b >> 3) {
            case 0: base = A_q; break;
            case 1: base = B_q; break;
            case 2: base = A_v; break;
            default: base = B_v; break;
        }
        base += (b & 7) * (RR * DD);
        float s = 0.f;
        for (int i = threadIdx.x; i < RR * DD; i += 256) {
            float v = base[i];
            s = fmaf(v, v, s);
        }
        #pragma unroll
        for (int off = 32; off > 0; off >>= 1) s += __shfl_down(s, off);
        if ((threadIdx.x & 63) == 0) ws4[threadIdx.x >> 6] = s;
        __syncthreads();
        if (threadIdx.x == 0)
            norms[b] = sqrtf(ws4[0] + ws4[1] + ws4[2] + ws4[3]);
    } else {
        const int idx = ((b - 32) * 256 + threadIdx.x) * 8;
        const float4 v0 = *(const float4*)(x + idx);
        const float4 v1 = *(const float4*)(x + idx + 4);
        bf16x8 o = { (bf16)v0.x, (bf16)v0.y, (bf16)v0.z, (bf16)v0.w,
                     (bf16)v1.x, (bf16)v1.y, (bf16)v1.z, (bf16)v1.w };
        *(bf16x8*)(xb + idx) = o;
    }
}

// ----------------------------------------------------------------- fold ----
// Wc[row] = bf16(qkv_w[row] + sum_i c[row][i] * Acat[i][:]) for q/v thirds;
// plain bf16 cast for the k third. Softmax gate + norm scaling computed
// inline per block. grid = (3, 288).  (unchanged, verified)
__global__ __launch_bounds__(256) void fold_kernel(
    const float* __restrict__ qkv_w,
    const float* __restrict__ A_q, const float* __restrict__ la_q,
    const float* __restrict__ B_q, const float* __restrict__ lb_q,
    const float* __restrict__ A_v, const float* __restrict__ la_v,
    const float* __restrict__ B_v, const float* __restrict__ lb_v,
    const float* __restrict__ gate_logits, const float* __restrict__ alpha,
    const float* __restrict__ norms, bf16* __restrict__ Wc)
{
    const int tid = threadIdx.x;
    const int d = blockIdx.x * 256 + tid;
    const int gy = blockIdx.y;

    if (gy >= 96 && gy < 192) {           // k third: pure cast
        const int rowbase = DD + (gy - 96) * 8;
        #pragma unroll
        for (int j = 0; j < 8; ++j) {
            const int row = rowbase + j;
            Wc[row * DD + d] = (bf16)qkv_w[row * DD + d];
        }
        return;
    }

    __shared__ float c_lds[8 * KRANK];
    __shared__ float sc_sh[TT];
    __shared__ float acur_sh;

    const bool is_v = (gy >= 192);
    const int e0 = (is_v ? gy - 192 : gy) * 8;
    const float* Astack = is_v ? A_v : A_q;
    const float* la     = is_v ? la_v : la_q;
    const float* Bmat   = is_v ? B_v : B_q;
    const float* lb     = is_v ? lb_v : lb_q;
    const float* nA     = norms + (is_v ? 16 : 0);
    const float* nB     = norms + (is_v ? 24 : 8);
    const int rowbase   = (is_v ? 2 * DD : 0) + e0;

    if (tid == 0) {
        float mx = gate_logits[0];
        for (int t = 1; t < TT; ++t) mx = fmaxf(mx, gate_logits[t]);
        float e[TT], s = 0.f;
        for (int t = 0; t < TT; ++t) { e[t] = __expf(gate_logits[t] - mx); s += e[t]; }
        for (int t = 0; t < TT; ++t) sc_sh[t] = (e[t] / s) / (nA[t] * nB[t]);
        acur_sh = alpha[TT];
    }
    __syncthreads();

    for (int idx = tid; idx < 8 * KRANK; idx += 256) {
        const int j = idx / KRANK, i = idx - j * KRANK;
        const int e = e0 + j;
        float v;
        if (i < TT * RR) {
            const int t = i >> 4, r = i & 15;
            v = sc_sh[t] * Bmat[(t * DD + e) * RR + r];
        } else {
            v = acur_sh * lb[e * RR + (i - TT * RR)];
        }
        c_lds[j * KRANK + i] = v;
    }
    __syncthreads();

    float acc[8] = {0.f, 0.f, 0.f, 0.f, 0.f, 0.f, 0.f, 0.f};

    for (int i = 0; i < TT * RR; i += 4) {
        const float a0 = Astack[(i + 0) * DD + d];
        const float a1 = Astack[(i + 1) * DD + d];
        const float a2 = Astack[(i + 2) * DD + d];
        const float a3 = Astack[(i + 3) * DD + d];
        #pragma unroll
        for (int j = 0; j < 8; ++j) {
            const float4 cv = *(const float4*)&c_lds[j * KRANK + i];
            acc[j] = fmaf(a0, cv.x, fmaf(a1, cv.y, fmaf(a2, cv.z, fmaf(a3, cv.w, acc[j]))));
        }
    }
    #pragma unroll
    for (int i = 0; i < RR; i += 4) {
        const float a0 = la[(i + 0) * DD + d];
        const float a1 = la[(i + 1) * DD + d];
        const float a2 = la[(i + 2) * DD + d];
        const float a3 = la[(i + 3) * DD + d];
        #pragma unroll
        for (int j = 0; j < 8; ++j) {
            const float4 cv = *(const float4*)&c_lds[j * KRANK + TT * RR + i];
            acc[j] = fmaf(a0, cv.x, fmaf(a1, cv.y, fmaf(a2, cv.z, fmaf(a3, cv.w, acc[j]))));
        }
    }

    #pragma unroll
    for (int j = 0; j < 8; ++j) {
        const int row = rowbase + j;
        Wc[row * DD + d] = (bf16)(qkv_w[row * DD + d] + acc[j]);
    }
}

// ----------------------------------------------------------------- gemm ----
// C[TOK,NOUT] = Xbf[TOK,DD] @ Wc[NOUT,DD]^T + bias.
// R9: occupancy fix. R8 counters: MfmaUtil 22%, Occupancy 16%, HBM 25% —
// latency/sync-bound, nothing near a roofline. Root cause theory: 52KB LDS
// pinned residency at 2 blocks/CU (= R2-R5's "~25% occupancy regardless");
// barrier lockstep within a block means only ONE other independent block
// exists to absorb each drain (m114: cross-block overlap is what hides the
// m97 barrier drain; m97 itself ran ~3 blocks/CU).
// Change: tile 128x192, BK=64, SINGLE 40KB LDS buffer -> 3 blocks/CU
// (120KB <= 160KB), grid = 64m x 12n = 768 = exactly 3x256 = one full
// round. launch_bounds(256,3) caps VGPR at 170 (acc 4x6 = 96 regs + frags
// ~40 -> fits, no spill expected; R3's spills were with 144-reg acc).
// Reverted to the R6-proven conflict-free BK=64 swizzle (R8's BK=32
// variant was 4-way conflicted: 2.55M SQ_LDS_BANK_CONFLICT) and the
// R6 full-drain __syncthreads() loop — the 3rd resident block does the
// hiding, not source pipelining (m99/m100: dbuf ~= single when
// co-resident waves overlap).
// Per wave: 64x96 output = 4x6 16x16 tiles, 48 MFMA per K-step.
__global__ __launch_bounds__(256, 3) void gemm_kernel(
    const bf16* __restrict__ A, const bf16* __restrict__ B,
    const float* __restrict__ bias, float* __restrict__ C)
{
    __shared__ __align__(16) char smem[40960];  // A 128x64 bf16 (16KB) + B 192x64 bf16 (24KB)
    bf16* const lds_a = (bf16*)smem;
    bf16* const lds_b = (bf16*)(smem + 16384);

    const int tid  = threadIdx.x;
    const int lane = tid & 63;
    const int wave = tid >> 6;

    // XCD swizzle: 768 blocks = 8 XCD x (8 m-tiles x 12 n-tiles)
    const int flat  = blockIdx.x;
    const int xcd   = flat & 7;
    const int local = flat >> 3;           // 0..95
    const int mb    = xcd * 8 + (local & 7);   // 0..63
    const int nb    = local >> 3;              // 0..11
    const int m0 = mb * 128;
    const int n0 = nb * 192;

    // 4 waves: 2x2, each computes 64x96 (4x6 tiles of 16x16)
    const int wm = (wave >> 1) * 64;
    const int wn = (wave & 1) * 96;

    // staging: lane l -> slot l (16B) within a 1KB chunk (8 rows x 64 bf16).
    // logical row = l>>3, logical 16B chunk = (l&7) ^ (l>>3)  (XOR swizzle,
    // R6-verified: 0 bank conflicts).
    const int srow = lane >> 3;                    // 0..7
    const int scol = ((lane & 7) ^ srow) * 8;      // swizzled col (bf16 units)

    floatx4 acc[4][6];
    #pragma unroll
    for (int i = 0; i < 4; ++i)
        #pragma unroll
        for (int j = 0; j < 6; ++j)
            acc[i][j] = (floatx4){0.f, 0.f, 0.f, 0.f};

    const bf16* const gA = A + (m0 + srow) * DD + scol;
    const bf16* const gB = B + (n0 + srow) * DD + scol;

    for (int kt = 0; kt < DD / 64; ++kt) {
        const int k0 = kt * 64;
        // stage A: 16 chunks of 8 rows; B: 24 chunks. round-robin by wave
        // -> 10 chunks per wave.
        #pragma unroll
        for (int i = 0; i < 4; ++i) {
            const int j = i * 4 + wave;            // 0..15
            gl_lds16(gA + j * 8 * DD + k0, &lds_a[j * 512]);
        }
        #pragma unroll
        for (int i = 0; i < 6; ++i) {
            const int j = i * 4 + wave;            // 0..23
            gl_lds16(gB + j * 8 * DD + k0, &lds_b[j * 512]);
        }
        __syncthreads();   // drains gl_lds (vmcnt) — tiles visible to all

        #pragma unroll
        for (int ks = 0; ks < 2; ++ks) {
            const int c_log = ks * 4 + (lane >> 4); // 16B chunk index 0..7
            bf16x8 af[4];
            #pragma unroll
            for (int mt = 0; mt < 4; ++mt) {
                const int r = wm + mt * 16 + (lane & 15);
                af[mt] = *(const bf16x8*)&lds_a[r * 64 + ((c_log ^ (r & 7)) * 8)];
            }
            #pragma unroll
            for (int nt = 0; nt < 6; ++nt) {
                const int r = wn + nt * 16 + (lane & 15);
                const bf16x8 bfr = *(const bf16x8*)&lds_b[r * 64 + ((c_log ^ (r & 7)) * 8)];
                #pragma unroll
                for (int mt = 0; mt < 4; ++mt)
                    acc[mt][nt] = __builtin_amdgcn_mfma_f32_16x16x32_bf16(
                        af[mt], bfr, acc[mt][nt], 0, 0, 0);
            }
        }
        __syncthreads();   // frees LDS buffer for next tile
    }

    // epilogue: direct stores. C/D layout col=lane&15, row=(lane>>4)*4+reg
    const int cr = (lane >> 4) * 4;
    const int cc = lane & 15;
    #pragma unroll
    for (int nt = 0; nt < 6; ++nt) {
        const int gn = n0 + wn + nt * 16 + cc;
        const float bv = bias[gn];
        #pragma unroll
        for (int mt = 0; mt < 4; ++mt) {
            const int gmb = m0 + wm + mt * 16 + cr;
            #pragma unroll
            for (int r = 0; r < 4; ++r)
                C[(gmb + r) * NOUT + gn] = acc[mt][nt][r] + bv;
        }
    }
}

// --------------------------------------------------------------- launch ----
extern "C" void kernel_launch(void* const* d_in, const int* in_sizes, int n_in,
                              void* d_out, int out_size, void* d_ws, size_t ws_size,
                              hipStream_t stream)
{
    const float* x           = (const float*)d_in[0];
    const float* qkv_w       = (const float*)d_in[1];
    const float* qkv_b       = (const float*)d_in[2];
    const float* la_q        = (const float*)d_in[3];
    const float* lb_q        = (const float*)d_in[4];
    const float* la_v        = (const float*)d_in[5];
    const float* lb_v        = (const float*)d_in[6];
    const float* A_q         = (const float*)d_in[7];
    const float* B_q         = (const float*)d_in[8];
    const float* A_v         = (const float*)d_in[9];
    const float* B_v         = (const float*)d_in[10];
    const float* gate_logits = (const float*)d_in[11];
    const float* alpha       = (const float*)d_in[12];
    float* out = (float*)d_out;

    char* ws = (char*)d_ws;
    bf16*  Xbf    = (bf16*)ws;                                  // 12,582,912 B
    bf16*  Wc     = (bf16*)(ws + 12582912);                     //  3,538,944 B
    float* norms  = (float*)(ws + 12582912 + 3538944);          // 32 floats

    prep_kernel<<<32 + TOK * DD / 2048, 256, 0, stream>>>(A_q, B_q, A_v, B_v,
                                                          x, Xbf, norms);
    fold_kernel<<<dim3(3, 288), 256, 0, stream>>>(qkv_w,
                                                  A_q, la_q, B_q, lb_q,
                                                  A_v, la_v, B_v, lb_v,
                                                  gate_logits, alpha, norms, Wc);
    gemm_kernel<<<768, 256, 0, stream>>>(Xbf, Wc, qkv_b, out);
}